// Round 2
// baseline (376.700 us; speedup 1.0000x reference)
//
#include <hip/hip_runtime.h>

// Problem constants: B=2, L=2048, D=1024, H=16, DH=64, BH=B*H=32, M=B*L=4096
// SCALE = DH^-0.5 = 0.125 (exact power of two -> folded into Q at projection time)

typedef __attribute__((ext_vector_type(8))) short short8;
typedef __attribute__((ext_vector_type(8))) __bf16 bf16x8;
typedef __attribute__((ext_vector_type(4))) float f32x4;

#define GLDS16(gp, lp)                                                         \
  __builtin_amdgcn_global_load_lds(                                            \
      (const __attribute__((address_space(1))) void*)(gp),                     \
      (__attribute__((address_space(3))) void*)(lp), 16, 0, 0)

__device__ __forceinline__ unsigned short f2bf(float f) {
  unsigned u = __builtin_bit_cast(unsigned, f);
  u += 0x7fffu + ((u >> 16) & 1u);   // RNE
  return (unsigned short)(u >> 16);
}

// ---------------- fused fp32 -> bf16 conversion ----------------
__global__ __launch_bounds__(256) void convert_all(
    const float* __restrict__ x, const float* __restrict__ wq,
    const float* __restrict__ wk, const float* __restrict__ wv,
    const float* __restrict__ wo, unsigned short* __restrict__ xb,
    unsigned short* __restrict__ wqkv, unsigned short* __restrict__ wob) {
  const int X4 = (2 * 2048 * 1024) / 4;
  const int W4 = (1024 * 1024) / 4;
  const int total = X4 + 4 * W4;
  for (int i = blockIdx.x * 256 + threadIdx.x; i < total;
       i += gridDim.x * 256) {
    const float* src; unsigned short* dst; int off;
    if (i < X4)               { src = x;  dst = xb;                   off = i; }
    else if (i < X4 + W4)     { src = wq; dst = wqkv;                 off = i - X4; }
    else if (i < X4 + 2 * W4) { src = wk; dst = wqkv + 1024 * 1024;   off = i - X4 - W4; }
    else if (i < X4 + 3 * W4) { src = wv; dst = wqkv + 2 * 1024 * 1024; off = i - X4 - 2 * W4; }
    else                      { src = wo; dst = wob;                  off = i - X4 - 3 * W4; }
    float4 v = ((const float4*)src)[off];
    uint2 o;
    o.x = (unsigned)f2bf(v.x) | ((unsigned)f2bf(v.y) << 16);
    o.y = (unsigned)f2bf(v.z) | ((unsigned)f2bf(v.w) << 16);
    ((uint2*)dst)[off] = o;
  }
}

// ---------------- 128x128 bf16 GEMM, C = A * B^T (m97 structure) ----------------
template <int MODE>
__global__ __launch_bounds__(256, 2) void gemm_bt(
    const unsigned short* __restrict__ A, const unsigned short* __restrict__ Bw,
    unsigned short* __restrict__ o_q, unsigned short* __restrict__ o_k,
    unsigned short* __restrict__ o_vT, const float* __restrict__ bias,
    float* __restrict__ o_f) {
  constexpr int K = 1024;
  __shared__ unsigned short As[128 * 32];
  __shared__ unsigned short Bs[128 * 32];
  const int t = threadIdx.x;
  const int w = t >> 6;
  const int lane = t & 63;
  const int g = lane >> 4;
  const int q16 = lane & 15;
  const int wm = w >> 1, wn = w & 1;
  const int bn0 = blockIdx.x * 128, bm0 = blockIdx.y * 128;
  const int arow = t >> 2;
  const int acol = (t & 3) * 8;

  f32x4 acc[4][4];
  const f32x4 z4 = {0.f, 0.f, 0.f, 0.f};
#pragma unroll
  for (int i = 0; i < 4; ++i)
#pragma unroll
    for (int j = 0; j < 4; ++j) acc[i][j] = z4;

  for (int k0 = 0; k0 < K; k0 += 32) {
#pragma unroll
    for (int c = 0; c < 2; ++c) {
      GLDS16(A + (size_t)(bm0 + c * 64 + arow) * K + k0 + acol,
             As + c * 2048 + w * 512);
      GLDS16(Bw + (size_t)(bn0 + c * 64 + arow) * K + k0 + acol,
             Bs + c * 2048 + w * 512);
    }
    __syncthreads();
    bf16x8 af[4], bf[4];
#pragma unroll
    for (int i = 0; i < 4; ++i)
      af[i] = *(const bf16x8*)(As + (wm * 64 + i * 16 + q16) * 32 + g * 8);
#pragma unroll
    for (int j = 0; j < 4; ++j)
      bf[j] = *(const bf16x8*)(Bs + (wn * 64 + j * 16 + q16) * 32 + g * 8);
#pragma unroll
    for (int i = 0; i < 4; ++i)
#pragma unroll
      for (int j = 0; j < 4; ++j)
        acc[i][j] =
            __builtin_amdgcn_mfma_f32_16x16x32_bf16(af[i], bf[j], acc[i][j], 0, 0, 0);
    __syncthreads();
  }

  if constexpr (MODE == 0) {
    const int which = bn0 >> 10;
#pragma unroll
    for (int i = 0; i < 4; ++i)
#pragma unroll
      for (int j = 0; j < 4; ++j)
#pragma unroll
        for (int r = 0; r < 4; ++r) {
          const int m = bm0 + wm * 64 + i * 16 + g * 4 + r;
          const int n = (bn0 & 1023) + wn * 64 + j * 16 + q16;
          const float v = acc[i][j][r];
          const int bb = m >> 11, lp = m & 2047;
          const int h = n >> 6, d = n & 63;
          const int bh = bb * 16 + h;
          if (which == 0)
            o_q[((size_t)bh * 2048 + lp) * 64 + d] = f2bf(v * 0.125f);
          else if (which == 1)
            o_k[((size_t)bh * 2048 + lp) * 64 + d] = f2bf(v);
          else
            o_vT[((size_t)bh * 64 + d) * 2048 + lp] = f2bf(v);
        }
  } else {
#pragma unroll
    for (int i = 0; i < 4; ++i)
#pragma unroll
      for (int j = 0; j < 4; ++j)
#pragma unroll
        for (int r = 0; r < 4; ++r) {
          const int m = bm0 + wm * 64 + i * 16 + g * 4 + r;
          const int n = bn0 + wn * 64 + j * 16 + q16;
          o_f[(size_t)m * 1024 + n] = acc[i][j][r] + bias[n];
        }
  }
}

// ---------------- flash attention (register double-buffered pipeline) --------
// grid = 32 heads * 32 q-tiles; block = 4 independent waves, each owns 16 q-rows.
// Unroll-by-2 over kv tiles: next tile's K+mask loads issue BEFORE the current
// tile's softmax chain; V loads issue at the top of the compute phase so their
// (L2-hit) latency hides under QK^T+softmax. Keeps ~10 16B/lane loads in
// flight per wave -> BW-bound on the 512MB mask stream instead of latency-bound.
__global__ __launch_bounds__(256, 4) void attn_kernel(
    const unsigned short* __restrict__ qb, const unsigned short* __restrict__ kb,
    const unsigned short* __restrict__ vT, const float* __restrict__ mask,
    unsigned short* __restrict__ hb) {
  __shared__ unsigned short Plds[4][16][40];
  const int bid = blockIdx.x;
  const int bh = bid >> 5, qt = bid & 31;
  const int t = threadIdx.x, w = t >> 6, lane = t & 63;
  const int g = lane >> 4, q16 = lane & 15;
  const int qrow = qt * 64 + w * 16;

  const unsigned short* qptr = qb + ((size_t)bh * 2048 + qrow + q16) * 64 + g * 8;
  bf16x8 qf0 = *(const bf16x8*)(qptr);
  bf16x8 qf1 = *(const bf16x8*)(qptr + 32);

  f32x4 O[4];
  const f32x4 z4 = {0.f, 0.f, 0.f, 0.f};
#pragma unroll
  for (int dt = 0; dt < 4; ++dt) O[dt] = z4;
  float mrun = -1e30f, lsum = 0.f;

  const float* mrow = mask + ((size_t)bh * 2048 + qrow + q16) * 2048 + g * 4;
  const unsigned short* kbase = kb + ((size_t)bh * 2048 + q16) * 64 + g * 8;
  const unsigned short* vbase = vT + (size_t)bh * 64 * 2048 + g * 8;

  bf16x8 kA[4], kB[4];
  f32x4 mA[2], mB[2];

#define LOAD_KM(kvb, kk, mm)                                                   \
  do {                                                                         \
    const unsigned short* kp_ = kbase + (size_t)(kvb) * 64;                    \
    kk[0] = *(const bf16x8*)(kp_);                                             \
    kk[1] = *(const bf16x8*)(kp_ + 32);                                        \
    kk[2] = *(const bf16x8*)(kp_ + 1024);                                      \
    kk[3] = *(const bf16x8*)(kp_ + 1024 + 32);                                 \
    mm[0] = *(const f32x4*)(mrow + (kvb));                                     \
    mm[1] = *(const f32x4*)(mrow + (kvb) + 16);                                \
  } while (0)

#define COMPUTE(kk, mm, kvb)                                                   \
  do {                                                                         \
    /* issue V loads early: latency hides under QK^T + softmax */              \
    bf16x8 vf[4];                                                              \
    const unsigned short* vp_ = vbase + (kvb);                                 \
    _Pragma("unroll") for (int dt = 0; dt < 4; ++dt)                           \
        vf[dt] = *(const bf16x8*)(vp_ + (size_t)(dt * 16 + q16) * 2048);       \
    f32x4 S0 = z4, S1 = z4;                                                    \
    S0 = __builtin_amdgcn_mfma_f32_16x16x32_bf16(kk[0], qf0, S0, 0, 0, 0);     \
    S0 = __builtin_amdgcn_mfma_f32_16x16x32_bf16(kk[1], qf1, S0, 0, 0, 0);     \
    S1 = __builtin_amdgcn_mfma_f32_16x16x32_bf16(kk[2], qf0, S1, 0, 0, 0);     \
    S1 = __builtin_amdgcn_mfma_f32_16x16x32_bf16(kk[3], qf1, S1, 0, 0, 0);     \
    S0 += mm[0];                                                               \
    S1 += mm[1];                                                               \
    float pm = fmaxf(fmaxf(fmaxf(S0[0], S0[1]), fmaxf(S0[2], S0[3])),          \
                     fmaxf(fmaxf(S1[0], S1[1]), fmaxf(S1[2], S1[3])));         \
    pm = fmaxf(pm, __shfl_xor(pm, 16));                                        \
    pm = fmaxf(pm, __shfl_xor(pm, 32));                                        \
    const float mnew = fmaxf(mrun, pm);                                        \
    const float alpha = __expf(mrun - mnew);                                   \
    float p0[4], p1[4];                                                        \
    float rs = 0.f;                                                            \
    _Pragma("unroll") for (int r = 0; r < 4; ++r) {                            \
      p0[r] = __expf(S0[r] - mnew);                                            \
      p1[r] = __expf(S1[r] - mnew);                                            \
      rs += p0[r] + p1[r];                                                     \
    }                                                                          \
    rs += __shfl_xor(rs, 16);                                                  \
    rs += __shfl_xor(rs, 32);                                                  \
    lsum = lsum * alpha + rs;                                                  \
    mrun = mnew;                                                               \
    float ar[4];                                                               \
    _Pragma("unroll") for (int r = 0; r < 4; ++r) ar[r] = __shfl(alpha, g * 4 + r); \
    _Pragma("unroll") for (int dt = 0; dt < 4; ++dt)                           \
        _Pragma("unroll") for (int r = 0; r < 4; ++r) O[dt][r] *= ar[r];       \
    uint2 pw0, pw1;                                                            \
    pw0.x = (unsigned)f2bf(p0[0]) | ((unsigned)f2bf(p0[1]) << 16);             \
    pw0.y = (unsigned)f2bf(p0[2]) | ((unsigned)f2bf(p0[3]) << 16);             \
    pw1.x = (unsigned)f2bf(p1[0]) | ((unsigned)f2bf(p1[1]) << 16);             \
    pw1.y = (unsigned)f2bf(p1[2]) | ((unsigned)f2bf(p1[3]) << 16);             \
    *(uint2*)&Plds[w][q16][g * 4] = pw0;                                       \
    *(uint2*)&Plds[w][q16][16 + g * 4] = pw1;                                  \
    bf16x8 pf = *(const bf16x8*)&Plds[w][q16][g * 8];                          \
    _Pragma("unroll") for (int dt = 0; dt < 4; ++dt)                           \
        O[dt] = __builtin_amdgcn_mfma_f32_16x16x32_bf16(pf, vf[dt], O[dt], 0, 0, 0); \
  } while (0)

  LOAD_KM(0, kA, mA);
  for (int kvb = 0; kvb < 2048; kvb += 64) {
    LOAD_KM(kvb + 32, kB, mB);
    COMPUTE(kA, mA, kvb);
    {
      const int kvn = (kvb + 64 < 2048) ? kvb + 64 : 0;  // clamped (harmless re-read)
      LOAD_KM(kvn, kA, mA);
    }
    COMPUTE(kB, mB, kvb + 32);
  }
#undef LOAD_KM
#undef COMPUTE

  float li[4];
#pragma unroll
  for (int r = 0; r < 4; ++r) li[r] = 1.f / __shfl(lsum, g * 4 + r);
  const int b = bh >> 4, h = bh & 15;
#pragma unroll
  for (int dt = 0; dt < 4; ++dt)
#pragma unroll
    for (int r = 0; r < 4; ++r) {
      const int qg = qrow + g * 4 + r;
      hb[((size_t)b * 2048 + qg) * 1024 + h * 64 + dt * 16 + q16] =
          f2bf(O[dt][r] * li[r]);
    }
}

extern "C" void kernel_launch(void* const* d_in, const int* in_sizes, int n_in,
                              void* d_out, int out_size, void* d_ws,
                              size_t ws_size, hipStream_t stream) {
  const float* x    = (const float*)d_in[0];
  const float* mask = (const float*)d_in[1];
  const float* wq   = (const float*)d_in[2];
  const float* wk   = (const float*)d_in[3];
  const float* wv   = (const float*)d_in[4];
  const float* wo   = (const float*)d_in[5];
  const float* bo   = (const float*)d_in[6];
  float* out = (float*)d_out;
  char* ws = (char*)d_ws;

  unsigned short* xb   = (unsigned short*)(ws);                        // 8 MiB
  unsigned short* wqkv = (unsigned short*)(ws + 8u * 1024 * 1024);     // 6 MiB
  unsigned short* wob  = (unsigned short*)(ws + 14u * 1024 * 1024);    // 2 MiB
  unsigned short* qbuf = (unsigned short*)(ws + 16u * 1024 * 1024);    // 8 MiB
  unsigned short* kbuf = (unsigned short*)(ws + 24u * 1024 * 1024);    // 8 MiB
  unsigned short* vTb  = (unsigned short*)(ws + 32u * 1024 * 1024);    // 8 MiB
  unsigned short* hb   = (unsigned short*)(ws + 40u * 1024 * 1024);    // 8 MiB
  (void)in_sizes; (void)n_in; (void)out_size; (void)ws_size;

  convert_all<<<2048, 256, 0, stream>>>(x, wq, wk, wv, wo, xb, wqkv, wob);
  gemm_bt<0><<<dim3(24, 32), 256, 0, stream>>>(xb, wqkv, qbuf, kbuf, vTb,
                                               nullptr, nullptr);
  attn_kernel<<<1024, 256, 0, stream>>>(qbuf, kbuf, vTb, mask, hb);
  gemm_bt<1><<<dim3(8, 32), 256, 0, stream>>>(hb, wob, nullptr, nullptr,
                                              nullptr, bo, out);
}

// Round 3
// 361.380 us; speedup vs baseline: 1.0424x; 1.0424x over previous
//
#include <hip/hip_runtime.h>

// Problem constants: B=2, L=2048, D=1024, H=16, DH=64, BH=B*H=32, M=B*L=4096
// SCALE = DH^-0.5 = 0.125 (exact power of two -> folded into Q at projection time)

typedef __attribute__((ext_vector_type(8))) short short8;
typedef __attribute__((ext_vector_type(8))) __bf16 bf16x8;
typedef __attribute__((ext_vector_type(4))) float f32x4;

#define GLDS16(gp, lp)                                                         \
  __builtin_amdgcn_global_load_lds(                                            \
      (const __attribute__((address_space(1))) void*)(gp),                     \
      (__attribute__((address_space(3))) void*)(lp), 16, 0, 0)

__device__ __forceinline__ unsigned short f2bf(float f) {
  unsigned u = __builtin_bit_cast(unsigned, f);
  u += 0x7fffu + ((u >> 16) & 1u);   // RNE
  return (unsigned short)(u >> 16);
}

// ---------------- fused fp32 -> bf16 conversion ----------------
__global__ __launch_bounds__(256) void convert_all(
    const float* __restrict__ x, const float* __restrict__ wq,
    const float* __restrict__ wk, const float* __restrict__ wv,
    const float* __restrict__ wo, unsigned short* __restrict__ xb,
    unsigned short* __restrict__ wqkv, unsigned short* __restrict__ wob) {
  const int X4 = (2 * 2048 * 1024) / 4;
  const int W4 = (1024 * 1024) / 4;
  const int total = X4 + 4 * W4;
  for (int i = blockIdx.x * 256 + threadIdx.x; i < total;
       i += gridDim.x * 256) {
    const float* src; unsigned short* dst; int off;
    if (i < X4)               { src = x;  dst = xb;                   off = i; }
    else if (i < X4 + W4)     { src = wq; dst = wqkv;                 off = i - X4; }
    else if (i < X4 + 2 * W4) { src = wk; dst = wqkv + 1024 * 1024;   off = i - X4 - W4; }
    else if (i < X4 + 3 * W4) { src = wv; dst = wqkv + 2 * 1024 * 1024; off = i - X4 - 2 * W4; }
    else                      { src = wo; dst = wob;                  off = i - X4 - 3 * W4; }
    float4 v = ((const float4*)src)[off];
    uint2 o;
    o.x = (unsigned)f2bf(v.x) | ((unsigned)f2bf(v.y) << 16);
    o.y = (unsigned)f2bf(v.z) | ((unsigned)f2bf(v.w) << 16);
    ((uint2*)dst)[off] = o;
  }
}

// ---------------- 128x128 bf16 GEMM, C = A * B^T (m97 structure) ----------------
template <int MODE>
__global__ __launch_bounds__(256, 2) void gemm_bt(
    const unsigned short* __restrict__ A, const unsigned short* __restrict__ Bw,
    unsigned short* __restrict__ o_q, unsigned short* __restrict__ o_k,
    unsigned short* __restrict__ o_vT, const float* __restrict__ bias,
    float* __restrict__ o_f) {
  constexpr int K = 1024;
  __shared__ unsigned short As[128 * 32];
  __shared__ unsigned short Bs[128 * 32];
  const int t = threadIdx.x;
  const int w = t >> 6;
  const int lane = t & 63;
  const int g = lane >> 4;
  const int q16 = lane & 15;
  const int wm = w >> 1, wn = w & 1;
  const int bn0 = blockIdx.x * 128, bm0 = blockIdx.y * 128;
  const int arow = t >> 2;
  const int acol = (t & 3) * 8;

  f32x4 acc[4][4];
  const f32x4 z4 = {0.f, 0.f, 0.f, 0.f};
#pragma unroll
  for (int i = 0; i < 4; ++i)
#pragma unroll
    for (int j = 0; j < 4; ++j) acc[i][j] = z4;

  for (int k0 = 0; k0 < K; k0 += 32) {
#pragma unroll
    for (int c = 0; c < 2; ++c) {
      GLDS16(A + (size_t)(bm0 + c * 64 + arow) * K + k0 + acol,
             As + c * 2048 + w * 512);
      GLDS16(Bw + (size_t)(bn0 + c * 64 + arow) * K + k0 + acol,
             Bs + c * 2048 + w * 512);
    }
    __syncthreads();
    bf16x8 af[4], bf[4];
#pragma unroll
    for (int i = 0; i < 4; ++i)
      af[i] = *(const bf16x8*)(As + (wm * 64 + i * 16 + q16) * 32 + g * 8);
#pragma unroll
    for (int j = 0; j < 4; ++j)
      bf[j] = *(const bf16x8*)(Bs + (wn * 64 + j * 16 + q16) * 32 + g * 8);
#pragma unroll
    for (int i = 0; i < 4; ++i)
#pragma unroll
      for (int j = 0; j < 4; ++j)
        acc[i][j] =
            __builtin_amdgcn_mfma_f32_16x16x32_bf16(af[i], bf[j], acc[i][j], 0, 0, 0);
    __syncthreads();
  }

  if constexpr (MODE == 0) {
    const int which = bn0 >> 10;
#pragma unroll
    for (int i = 0; i < 4; ++i)
#pragma unroll
      for (int j = 0; j < 4; ++j)
#pragma unroll
        for (int r = 0; r < 4; ++r) {
          const int m = bm0 + wm * 64 + i * 16 + g * 4 + r;
          const int n = (bn0 & 1023) + wn * 64 + j * 16 + q16;
          const float v = acc[i][j][r];
          const int bb = m >> 11, lp = m & 2047;
          const int h = n >> 6, d = n & 63;
          const int bh = bb * 16 + h;
          if (which == 0)
            o_q[((size_t)bh * 2048 + lp) * 64 + d] = f2bf(v * 0.125f);
          else if (which == 1)
            o_k[((size_t)bh * 2048 + lp) * 64 + d] = f2bf(v);
          else
            o_vT[((size_t)bh * 64 + d) * 2048 + lp] = f2bf(v);
        }
  } else {
#pragma unroll
    for (int i = 0; i < 4; ++i)
#pragma unroll
      for (int j = 0; j < 4; ++j)
#pragma unroll
        for (int r = 0; r < 4; ++r) {
          const int m = bm0 + wm * 64 + i * 16 + g * 4 + r;
          const int n = bn0 + wn * 64 + j * 16 + q16;
          o_f[(size_t)m * 1024 + n] = acc[i][j][r] + bias[n];
        }
  }
}

// ---------------- flash attention, async mask staging ----------------
// grid = 1024 blocks (XCD-swizzled: 4 heads per XCD -> K/V L2-resident).
// Mask (the 512MB HBM stream) staged into LDS via global_load_lds, depth-4
// ring, issued 2 tiles ahead, counted vmcnt(4) + 1 barrier per tile.
// Chunk-XOR swizzle (source-side + read-side, involution) kills the 128B-stride
// bank conflict. K/V stay as register loads (L2-hit). Mask HBM latency is off
// the per-tile critical path -> mask-BW-bound.
__global__ __launch_bounds__(256, 4) void attn_kernel(
    const unsigned short* __restrict__ qb, const unsigned short* __restrict__ kb,
    const unsigned short* __restrict__ vT, const float* __restrict__ mask,
    unsigned short* __restrict__ hb) {
  __shared__ float Mst[4][64 * 32];           // 32 KB mask ring buffer
  __shared__ unsigned short Plds[4][16][40];  // 5 KB P round-trip
  const int orig = blockIdx.x;
  const int bid = (orig & 7) * 128 + (orig >> 3);  // bijective (1024 % 8 == 0)
  const int bh = bid >> 5, qt = bid & 31;
  const int t = threadIdx.x, w = t >> 6, lane = t & 63;
  const int g = lane >> 4, q16 = lane & 15;
  const int qrow0 = qt * 64;
  const int qrow = qrow0 + w * 16;

  const unsigned short* qptr = qb + ((size_t)bh * 2048 + qrow + q16) * 64 + g * 8;
  bf16x8 qf0 = *(const bf16x8*)(qptr);
  bf16x8 qf1 = *(const bf16x8*)(qptr + 32);

  f32x4 O[4];
  const f32x4 z4 = {0.f, 0.f, 0.f, 0.f};
#pragma unroll
  for (int dt = 0; dt < 4; ++dt) O[dt] = z4;
  float mrun = -1e30f, lsum = 0.f;

  const unsigned short* kbase = kb + ((size_t)bh * 2048 + q16) * 64 + g * 8;
  const unsigned short* vbase = vT + (size_t)bh * 64 * 2048 + g * 8;

  // Staging source addresses (per lane, swizzled chunk): slot f = (w*2+j)*64+lane
  // holds logical (row = f>>3, chunk = (f&7) ^ (row&7)). LDS dest stays linear.
  const float* mbase = mask + ((size_t)bh * 2048 + qrow0) * 2048;
  const int fA = (w * 2 + 0) * 64 + lane;
  const int fB = (w * 2 + 1) * 64 + lane;
  const int rA = fA >> 3, cA = (fA & 7) ^ (rA & 7);
  const int rB = fB >> 3, cB = (fB & 7) ^ (rB & 7);
  const float* msrcA = mbase + (size_t)rA * 2048 + cA * 4;
  const float* msrcB = mbase + (size_t)rB * 2048 + cB * 4;

  // read-side swizzled LDS offsets (f32 units), fixed per lane
  const int moff0 = (w * 16 + q16) * 32 + ((g ^ (q16 & 7)) << 2);
  const int moff1 = (w * 16 + q16) * 32 + (((4 + g) ^ (q16 & 7)) << 2);

#define STAGE(ti)                                                              \
  do {                                                                         \
    const int bq_ = (ti) & 3;                                                  \
    const int kvb_ = ((ti) < 64 ? (ti) : 63) * 32;                             \
    GLDS16(msrcA + kvb_, &Mst[bq_][(w * 2 + 0) * 256]);                        \
    GLDS16(msrcB + kvb_, &Mst[bq_][(w * 2 + 1) * 256]);                        \
  } while (0)

  STAGE(0);
  STAGE(1);
  for (int tl = 0; tl < 64; ++tl) {
    STAGE(tl + 2);
    asm volatile("s_waitcnt vmcnt(4)" ::: "memory");
    __builtin_amdgcn_s_barrier();
    __builtin_amdgcn_sched_barrier(0);

    const int kvb = tl * 32, bq = tl & 3;
    // V loads issued early; latency hides under QK^T + softmax
    bf16x8 vf[4];
    const unsigned short* vp = vbase + kvb;
#pragma unroll
    for (int dt = 0; dt < 4; ++dt)
      vf[dt] = *(const bf16x8*)(vp + (size_t)(dt * 16 + q16) * 2048);
    const unsigned short* kp = kbase + (size_t)kvb * 64;
    bf16x8 kf0 = *(const bf16x8*)(kp);
    bf16x8 kf1 = *(const bf16x8*)(kp + 32);
    bf16x8 kf2 = *(const bf16x8*)(kp + 1024);
    bf16x8 kf3 = *(const bf16x8*)(kp + 1024 + 32);

    f32x4 S0 = z4, S1 = z4;
    S0 = __builtin_amdgcn_mfma_f32_16x16x32_bf16(kf0, qf0, S0, 0, 0, 0);
    S0 = __builtin_amdgcn_mfma_f32_16x16x32_bf16(kf1, qf1, S0, 0, 0, 0);
    S1 = __builtin_amdgcn_mfma_f32_16x16x32_bf16(kf2, qf0, S1, 0, 0, 0);
    S1 = __builtin_amdgcn_mfma_f32_16x16x32_bf16(kf3, qf1, S1, 0, 0, 0);

    S0 += *(const f32x4*)&Mst[bq][moff0];
    S1 += *(const f32x4*)&Mst[bq][moff1];

    float pm = fmaxf(fmaxf(fmaxf(S0[0], S0[1]), fmaxf(S0[2], S0[3])),
                     fmaxf(fmaxf(S1[0], S1[1]), fmaxf(S1[2], S1[3])));
    pm = fmaxf(pm, __shfl_xor(pm, 16));
    pm = fmaxf(pm, __shfl_xor(pm, 32));
    const float mnew = fmaxf(mrun, pm);
    const float alpha = __expf(mrun - mnew);
    float p0[4], p1[4];
    float rs = 0.f;
#pragma unroll
    for (int r = 0; r < 4; ++r) {
      p0[r] = __expf(S0[r] - mnew);
      p1[r] = __expf(S1[r] - mnew);
      rs += p0[r] + p1[r];
    }
    rs += __shfl_xor(rs, 16);
    rs += __shfl_xor(rs, 32);
    lsum = lsum * alpha + rs;
    mrun = mnew;

    float ar[4];
#pragma unroll
    for (int r = 0; r < 4; ++r) ar[r] = __shfl(alpha, g * 4 + r);
#pragma unroll
    for (int dt = 0; dt < 4; ++dt)
#pragma unroll
      for (int r = 0; r < 4; ++r) O[dt][r] *= ar[r];

    uint2 pw0, pw1;
    pw0.x = (unsigned)f2bf(p0[0]) | ((unsigned)f2bf(p0[1]) << 16);
    pw0.y = (unsigned)f2bf(p0[2]) | ((unsigned)f2bf(p0[3]) << 16);
    pw1.x = (unsigned)f2bf(p1[0]) | ((unsigned)f2bf(p1[1]) << 16);
    pw1.y = (unsigned)f2bf(p1[2]) | ((unsigned)f2bf(p1[3]) << 16);
    *(uint2*)&Plds[w][q16][g * 4] = pw0;
    *(uint2*)&Plds[w][q16][16 + g * 4] = pw1;
    bf16x8 pf = *(const bf16x8*)&Plds[w][q16][g * 8];
#pragma unroll
    for (int dt = 0; dt < 4; ++dt)
      O[dt] = __builtin_amdgcn_mfma_f32_16x16x32_bf16(pf, vf[dt], O[dt], 0, 0, 0);
  }
#undef STAGE

  float li[4];
#pragma unroll
  for (int r = 0; r < 4; ++r) li[r] = 1.f / __shfl(lsum, g * 4 + r);
  const int b = bh >> 4, h = bh & 15;
#pragma unroll
  for (int dt = 0; dt < 4; ++dt)
#pragma unroll
    for (int r = 0; r < 4; ++r) {
      const int qg = qrow + g * 4 + r;
      hb[((size_t)b * 2048 + qg) * 1024 + h * 64 + dt * 16 + q16] =
          f2bf(O[dt][r] * li[r]);
    }
}

extern "C" void kernel_launch(void* const* d_in, const int* in_sizes, int n_in,
                              void* d_out, int out_size, void* d_ws,
                              size_t ws_size, hipStream_t stream) {
  const float* x    = (const float*)d_in[0];
  const float* mask = (const float*)d_in[1];
  const float* wq   = (const float*)d_in[2];
  const float* wk   = (const float*)d_in[3];
  const float* wv   = (const float*)d_in[4];
  const float* wo   = (const float*)d_in[5];
  const float* bo   = (const float*)d_in[6];
  float* out = (float*)d_out;
  char* ws = (char*)d_ws;

  unsigned short* xb   = (unsigned short*)(ws);                        // 8 MiB
  unsigned short* wqkv = (unsigned short*)(ws + 8u * 1024 * 1024);     // 6 MiB
  unsigned short* wob  = (unsigned short*)(ws + 14u * 1024 * 1024);    // 2 MiB
  unsigned short* qbuf = (unsigned short*)(ws + 16u * 1024 * 1024);    // 8 MiB
  unsigned short* kbuf = (unsigned short*)(ws + 24u * 1024 * 1024);    // 8 MiB
  unsigned short* vTb  = (unsigned short*)(ws + 32u * 1024 * 1024);    // 8 MiB
  unsigned short* hb   = (unsigned short*)(ws + 40u * 1024 * 1024);    // 8 MiB
  (void)in_sizes; (void)n_in; (void)out_size; (void)ws_size;

  convert_all<<<2048, 256, 0, stream>>>(x, wq, wk, wv, wo, xb, wqkv, wob);
  gemm_bt<0><<<dim3(24, 32), 256, 0, stream>>>(xb, wqkv, qbuf, kbuf, vTb,
                                               nullptr, nullptr);
  attn_kernel<<<1024, 256, 0, stream>>>(qbuf, kbuf, vTb, mask, hb);
  gemm_bt<1><<<dim3(8, 32), 256, 0, stream>>>(hb, wob, nullptr, nullptr,
                                              nullptr, bo, out);
}

// Round 4
// 315.598 us; speedup vs baseline: 1.1936x; 1.1451x over previous
//
#include <hip/hip_runtime.h>

// Problem constants: B=2, L=2048, D=1024, H=16, DH=64, BH=B*H=32, M=B*L=4096
// SCALE = DH^-0.5 = 0.125 (exact power of two -> folded into Q at projection time)

typedef __attribute__((ext_vector_type(8))) short short8;
typedef __attribute__((ext_vector_type(8))) __bf16 bf16x8;
typedef __attribute__((ext_vector_type(4))) float f32x4;

#define GLDS16(gp, lp)                                                         \
  __builtin_amdgcn_global_load_lds(                                            \
      (const __attribute__((address_space(1))) void*)(gp),                     \
      (__attribute__((address_space(3))) void*)(lp), 16, 0, 0)

__device__ __forceinline__ unsigned short f2bf(float f) {
  unsigned u = __builtin_bit_cast(unsigned, f);
  u += 0x7fffu + ((u >> 16) & 1u);   // RNE
  return (unsigned short)(u >> 16);
}

// ---------------- fused fp32 -> bf16 conversion ----------------
__global__ __launch_bounds__(256) void convert_all(
    const float* __restrict__ x, const float* __restrict__ wq,
    const float* __restrict__ wk, const float* __restrict__ wv,
    const float* __restrict__ wo, unsigned short* __restrict__ xb,
    unsigned short* __restrict__ wqkv, unsigned short* __restrict__ wob) {
  const int X4 = (2 * 2048 * 1024) / 4;
  const int W4 = (1024 * 1024) / 4;
  const int total = X4 + 4 * W4;
  for (int i = blockIdx.x * 256 + threadIdx.x; i < total;
       i += gridDim.x * 256) {
    const float* src; unsigned short* dst; int off;
    if (i < X4)               { src = x;  dst = xb;                   off = i; }
    else if (i < X4 + W4)     { src = wq; dst = wqkv;                 off = i - X4; }
    else if (i < X4 + 2 * W4) { src = wk; dst = wqkv + 1024 * 1024;   off = i - X4 - W4; }
    else if (i < X4 + 3 * W4) { src = wv; dst = wqkv + 2 * 1024 * 1024; off = i - X4 - 2 * W4; }
    else                      { src = wo; dst = wob;                  off = i - X4 - 3 * W4; }
    float4 v = ((const float4*)src)[off];
    uint2 o;
    o.x = (unsigned)f2bf(v.x) | ((unsigned)f2bf(v.y) << 16);
    o.y = (unsigned)f2bf(v.z) | ((unsigned)f2bf(v.w) << 16);
    ((uint2*)dst)[off] = o;
  }
}

// ---------------- 128x128 bf16 GEMM, C = A * B^T (m97 structure) ----------------
template <int MODE>
__global__ __launch_bounds__(256, 2) void gemm_bt(
    const unsigned short* __restrict__ A, const unsigned short* __restrict__ Bw,
    unsigned short* __restrict__ o_q, unsigned short* __restrict__ o_k,
    unsigned short* __restrict__ o_vT, const float* __restrict__ bias,
    float* __restrict__ o_f) {
  constexpr int K = 1024;
  __shared__ unsigned short As[128 * 32];
  __shared__ unsigned short Bs[128 * 32];
  const int t = threadIdx.x;
  const int w = t >> 6;
  const int lane = t & 63;
  const int g = lane >> 4;
  const int q16 = lane & 15;
  const int wm = w >> 1, wn = w & 1;
  const int bn0 = blockIdx.x * 128, bm0 = blockIdx.y * 128;
  const int arow = t >> 2;
  const int acol = (t & 3) * 8;

  f32x4 acc[4][4];
  const f32x4 z4 = {0.f, 0.f, 0.f, 0.f};
#pragma unroll
  for (int i = 0; i < 4; ++i)
#pragma unroll
    for (int j = 0; j < 4; ++j) acc[i][j] = z4;

  for (int k0 = 0; k0 < K; k0 += 32) {
#pragma unroll
    for (int c = 0; c < 2; ++c) {
      GLDS16(A + (size_t)(bm0 + c * 64 + arow) * K + k0 + acol,
             As + c * 2048 + w * 512);
      GLDS16(Bw + (size_t)(bn0 + c * 64 + arow) * K + k0 + acol,
             Bs + c * 2048 + w * 512);
    }
    __syncthreads();
    bf16x8 af[4], bf[4];
#pragma unroll
    for (int i = 0; i < 4; ++i)
      af[i] = *(const bf16x8*)(As + (wm * 64 + i * 16 + q16) * 32 + g * 8);
#pragma unroll
    for (int j = 0; j < 4; ++j)
      bf[j] = *(const bf16x8*)(Bs + (wn * 64 + j * 16 + q16) * 32 + g * 8);
#pragma unroll
    for (int i = 0; i < 4; ++i)
#pragma unroll
      for (int j = 0; j < 4; ++j)
        acc[i][j] =
            __builtin_amdgcn_mfma_f32_16x16x32_bf16(af[i], bf[j], acc[i][j], 0, 0, 0);
    __syncthreads();
  }

  if constexpr (MODE == 0) {
    const int which = bn0 >> 10;
#pragma unroll
    for (int i = 0; i < 4; ++i)
#pragma unroll
      for (int j = 0; j < 4; ++j)
#pragma unroll
        for (int r = 0; r < 4; ++r) {
          const int m = bm0 + wm * 64 + i * 16 + g * 4 + r;
          const int n = (bn0 & 1023) + wn * 64 + j * 16 + q16;
          const float v = acc[i][j][r];
          const int bb = m >> 11, lp = m & 2047;
          const int h = n >> 6, d = n & 63;
          const int bh = bb * 16 + h;
          if (which == 0)
            o_q[((size_t)bh * 2048 + lp) * 64 + d] = f2bf(v * 0.125f);
          else if (which == 1)
            o_k[((size_t)bh * 2048 + lp) * 64 + d] = f2bf(v);
          else
            o_vT[((size_t)bh * 64 + d) * 2048 + lp] = f2bf(v);
        }
  } else {
#pragma unroll
    for (int i = 0; i < 4; ++i)
#pragma unroll
      for (int j = 0; j < 4; ++j)
#pragma unroll
        for (int r = 0; r < 4; ++r) {
          const int m = bm0 + wm * 64 + i * 16 + g * 4 + r;
          const int n = bn0 + wn * 64 + j * 16 + q16;
          o_f[(size_t)m * 1024 + n] = acc[i][j][r] + bias[n];
        }
  }
}

// ---------------- flash attention, fully LDS-staged pipeline ----------------
// NO register global loads in the loop: K, V, mask all arrive via
// global_load_lds. Per tile: vmcnt(2) -> s_barrier -> sched_barrier ->
// stage K/V(t+1) + mask(t+2) -> compute(t) from LDS. The counted vmcnt never
// drains the prefetch queue (the R3 bug: compiler vmcnt(0) before QK MFMA for
// register K loads). XOR-swizzled LDS (source-side preswizzle + swizzled
// read, involution) -> conflict-free b128 reads. LDS 45KB -> 3 blocks/CU.
__global__ __launch_bounds__(256, 3) void attn_kernel(
    const unsigned short* __restrict__ kb, const unsigned short* __restrict__ qb,
    const unsigned short* __restrict__ vT, const float* __restrict__ mask,
    unsigned short* __restrict__ hb) {
  __shared__ float Mst[3 * 2048];            // 24 KB mask ring (tile = 64q x 32kv f32)
  __shared__ unsigned short Kst[2 * 2048];   // 8 KB K ring (tile = 32kv x 64d bf16)
  __shared__ unsigned short Vst[2 * 2048];   // 8 KB V ring (tile = 64d x 32kv bf16)
  __shared__ unsigned short Plds[4][16][40]; // 5 KB P round-trip
  const int orig = blockIdx.x;
  const int bid = (orig & 7) * 128 + (orig >> 3);  // bijective (1024 % 8 == 0)
  const int bh = bid >> 5, qt = bid & 31;
  const int t = threadIdx.x, w = t >> 6, lane = t & 63;
  const int g = lane >> 4, q16 = lane & 15;
  const int qrow0 = qt * 64;
  const int qrow = qrow0 + w * 16;

  const unsigned short* qptr = qb + ((size_t)bh * 2048 + qrow + q16) * 64 + g * 8;
  bf16x8 qf0 = *(const bf16x8*)(qptr);
  bf16x8 qf1 = *(const bf16x8*)(qptr + 32);

  f32x4 O[4];
  const f32x4 z4 = {0.f, 0.f, 0.f, 0.f};
#pragma unroll
  for (int dt = 0; dt < 4; ++dt) O[dt] = z4;
  float mrun = -1e30f, lsum = 0.f;

  // ---- staging sources (pre-swizzled per lane; LDS dests are wave-uniform) ----
  // mask: wave w stages its own rows w*16..w*16+15 (8 chunks/row of 4 f32)
  const float* mbase = mask + ((size_t)bh * 2048 + qrow0) * 2048;
  const int fA = (w * 2 + 0) * 64 + lane;
  const int fB = (w * 2 + 1) * 64 + lane;
  const int rA = fA >> 3, cA = (fA & 7) ^ (rA & 7);
  const int rB = fB >> 3, cB = (fB & 7) ^ (rB & 7);
  const float* msrcA = mbase + (size_t)rA * 2048 + cA * 4;
  const float* msrcB = mbase + (size_t)rB * 2048 + cB * 4;
  // K: wave w stages kv-rows w*8..w*8+7 (8 chunks/row of 8 bf16)
  const int rK = w * 8 + (lane >> 3), cK = (lane & 7) ^ (rK & 7);
  const unsigned short* ksrc = kb + (size_t)bh * 2048 * 64 + (size_t)rK * 64 + cK * 8;
  // V^T: wave w stages d-rows w*16..w*16+15 (4 chunks/row of 8 bf16)
  const int rV = w * 16 + (lane >> 2), cV = (lane & 3) ^ ((rV >> 1) & 3);
  const unsigned short* vsrc = vT + (size_t)bh * 64 * 2048 + (size_t)rV * 2048 + cV * 8;

  // ---- swizzled read offsets (fixed per lane) ----
  const int kx0 = (g ^ (q16 & 7)) * 8;
  const int kx1 = ((g + 4) ^ (q16 & 7)) * 8;
  const int moff0 = (w * 16 + q16) * 32 + (g ^ (q16 & 7)) * 4;
  const int moff1 = (w * 16 + q16) * 32 + ((g + 4) ^ (q16 & 7)) * 4;
  const int vx = (g ^ ((q16 >> 1) & 3)) * 8;

#define STAGE_KV(ti)                                                           \
  do {                                                                         \
    const int kvb_ = ((ti) < 64 ? (ti) : 63) * 32;                             \
    const int b_ = (ti) & 1;                                                   \
    GLDS16(ksrc + (size_t)kvb_ * 64, Kst + b_ * 2048 + w * 512);               \
    GLDS16(vsrc + kvb_, Vst + b_ * 2048 + w * 512);                            \
  } while (0)
#define STAGE_M(ti, b_)                                                        \
  do {                                                                         \
    const int kvb_ = ((ti) < 64 ? (ti) : 63) * 32;                             \
    GLDS16(msrcA + kvb_, Mst + (b_)*2048 + (w * 2 + 0) * 256);                 \
    GLDS16(msrcB + kvb_, Mst + (b_)*2048 + (w * 2 + 1) * 256);                 \
  } while (0)

  STAGE_KV(0);     // K0 V0
  STAGE_M(0, 0);   // mask0
  STAGE_M(1, 1);   // mask1  (newest 2 ops -> vmcnt(2) waits K0,V0,mask0)

  int mb = 0;  // mask read buffer
  for (int tl = 0; tl < 64; ++tl) {
    asm volatile("s_waitcnt vmcnt(2)" ::: "memory");
    __builtin_amdgcn_s_barrier();
    __builtin_amdgcn_sched_barrier(0);

    STAGE_KV(tl + 1);
    {
      int msb = mb + 2;
      if (msb >= 3) msb -= 3;
      STAGE_M(tl + 2, msb);
    }

    const unsigned short* Kb = Kst + (tl & 1) * 2048;
    const unsigned short* Vb = Vst + (tl & 1) * 2048;
    const float* Mb = Mst + mb * 2048;

    // V frags issued early; lgkm latency hides under QK^T + softmax
    bf16x8 vf[4];
#pragma unroll
    for (int dt = 0; dt < 4; ++dt)
      vf[dt] = *(const bf16x8*)(Vb + (dt * 16 + q16) * 32 + vx);

    bf16x8 kf0 = *(const bf16x8*)(Kb + q16 * 64 + kx0);
    bf16x8 kf1 = *(const bf16x8*)(Kb + q16 * 64 + kx1);
    bf16x8 kf2 = *(const bf16x8*)(Kb + (16 + q16) * 64 + kx0);
    bf16x8 kf3 = *(const bf16x8*)(Kb + (16 + q16) * 64 + kx1);

    f32x4 S0 = z4, S1 = z4;
    S0 = __builtin_amdgcn_mfma_f32_16x16x32_bf16(kf0, qf0, S0, 0, 0, 0);
    S0 = __builtin_amdgcn_mfma_f32_16x16x32_bf16(kf1, qf1, S0, 0, 0, 0);
    S1 = __builtin_amdgcn_mfma_f32_16x16x32_bf16(kf2, qf0, S1, 0, 0, 0);
    S1 = __builtin_amdgcn_mfma_f32_16x16x32_bf16(kf3, qf1, S1, 0, 0, 0);

    S0 += *(const f32x4*)(Mb + moff0);
    S1 += *(const f32x4*)(Mb + moff1);

    float pm = fmaxf(fmaxf(fmaxf(S0[0], S0[1]), fmaxf(S0[2], S0[3])),
                     fmaxf(fmaxf(S1[0], S1[1]), fmaxf(S1[2], S1[3])));
    pm = fmaxf(pm, __shfl_xor(pm, 16));
    pm = fmaxf(pm, __shfl_xor(pm, 32));
    const float mnew = fmaxf(mrun, pm);
    const float alpha = __expf(mrun - mnew);
    float p0[4], p1[4];
    float rs = 0.f;
#pragma unroll
    for (int r = 0; r < 4; ++r) {
      p0[r] = __expf(S0[r] - mnew);
      p1[r] = __expf(S1[r] - mnew);
      rs += p0[r] + p1[r];
    }
    rs += __shfl_xor(rs, 16);
    rs += __shfl_xor(rs, 32);
    lsum = lsum * alpha + rs;
    mrun = mnew;

    float ar[4];
#pragma unroll
    for (int r = 0; r < 4; ++r) ar[r] = __shfl(alpha, g * 4 + r);
#pragma unroll
    for (int dt = 0; dt < 4; ++dt)
#pragma unroll
      for (int r = 0; r < 4; ++r) O[dt][r] *= ar[r];

    uint2 pw0, pw1;
    pw0.x = (unsigned)f2bf(p0[0]) | ((unsigned)f2bf(p0[1]) << 16);
    pw0.y = (unsigned)f2bf(p0[2]) | ((unsigned)f2bf(p0[3]) << 16);
    pw1.x = (unsigned)f2bf(p1[0]) | ((unsigned)f2bf(p1[1]) << 16);
    pw1.y = (unsigned)f2bf(p1[2]) | ((unsigned)f2bf(p1[3]) << 16);
    *(uint2*)&Plds[w][q16][g * 4] = pw0;
    *(uint2*)&Plds[w][q16][16 + g * 4] = pw1;
    bf16x8 pf = *(const bf16x8*)&Plds[w][q16][g * 8];
#pragma unroll
    for (int dt = 0; dt < 4; ++dt)
      O[dt] = __builtin_amdgcn_mfma_f32_16x16x32_bf16(pf, vf[dt], O[dt], 0, 0, 0);

    mb = (mb + 1 >= 3) ? mb + 1 - 3 : mb + 1;
  }
#undef STAGE_KV
#undef STAGE_M

  float li[4];
#pragma unroll
  for (int r = 0; r < 4; ++r) li[r] = 1.f / __shfl(lsum, g * 4 + r);
  const int b = bh >> 4, h = bh & 15;
#pragma unroll
  for (int dt = 0; dt < 4; ++dt)
#pragma unroll
    for (int r = 0; r < 4; ++r) {
      const int qg = qrow + g * 4 + r;
      hb[((size_t)b * 2048 + qg) * 1024 + h * 64 + dt * 16 + q16] =
          f2bf(O[dt][r] * li[r]);
    }
}

extern "C" void kernel_launch(void* const* d_in, const int* in_sizes, int n_in,
                              void* d_out, int out_size, void* d_ws,
                              size_t ws_size, hipStream_t stream) {
  const float* x    = (const float*)d_in[0];
  const float* mask = (const float*)d_in[1];
  const float* wq   = (const float*)d_in[2];
  const float* wk   = (const float*)d_in[3];
  const float* wv   = (const float*)d_in[4];
  const float* wo   = (const float*)d_in[5];
  const float* bo   = (const float*)d_in[6];
  float* out = (float*)d_out;
  char* ws = (char*)d_ws;

  unsigned short* xb   = (unsigned short*)(ws);                        // 8 MiB
  unsigned short* wqkv = (unsigned short*)(ws + 8u * 1024 * 1024);     // 6 MiB
  unsigned short* wob  = (unsigned short*)(ws + 14u * 1024 * 1024);    // 2 MiB
  unsigned short* qbuf = (unsigned short*)(ws + 16u * 1024 * 1024);    // 8 MiB
  unsigned short* kbuf = (unsigned short*)(ws + 24u * 1024 * 1024);    // 8 MiB
  unsigned short* vTb  = (unsigned short*)(ws + 32u * 1024 * 1024);    // 8 MiB
  unsigned short* hb   = (unsigned short*)(ws + 40u * 1024 * 1024);    // 8 MiB
  (void)in_sizes; (void)n_in; (void)out_size; (void)ws_size;

  convert_all<<<2048, 256, 0, stream>>>(x, wq, wk, wv, wo, xb, wqkv, wob);
  gemm_bt<0><<<dim3(24, 32), 256, 0, stream>>>(xb, wqkv, qbuf, kbuf, vTb,
                                               nullptr, nullptr);
  attn_kernel<<<1024, 256, 0, stream>>>(kbuf, qbuf, vTb, mask, hb);
  gemm_bt<1><<<dim3(8, 32), 256, 0, stream>>>(hb, wob, nullptr, nullptr,
                                              nullptr, bo, out);
}